// Round 7
// baseline (242.029 us; speedup 1.0000x reference)
//
#include <hip/hip_runtime.h>
#include <stdint.h>

// Problem constants
#define T_TOK 16384     // 32*512 tokens
#define NE 8            // experts
#define EPSV 1e-8f
#define MAXC128 136     // max 128-token chunks: 128 + 7 partials, rounded up
#define MAXC64  264     // max 64-token chunks: 256 + 7 partials, rounded up

// ws layout (byte offsets). Total ~56.8 MiB.
#define WS_PERM   0                         // int[16384]
#define WS_CNT    65536                     // int[8]
#define WS_CUR    65600                     // int[8]
#define WS_OFFS   65664                     // int[9]
#define WS_XS     131072                    // bf16[16512][1024] (slack rows for OOB-safe tile loads)
#define WS_WT     (WS_XS + 16512*1024*2)    // bf16[8][512][1024]  (W1|R1 transposed, B^T layout)
#define WS_H1     (WS_WT + 8*512*1024*2)    // bf16[16448][512] (64 slack rows)
#define WS_W2T    (WS_H1 + 16448*512*2)     // bf16[8][64][256]
#define WS_W3T    (WS_W2T + 8*64*256*2)     // bf16[8][32][64]
#define WS_W4T    (WS_W3T + 8*32*64*2)      // bf16[8][16][32]  (n>=14 zero)
#define WS_R2T    (WS_W4T + 8*16*32*2)      // bf16[8][16][256] (n>=3 zero)

typedef __attribute__((ext_vector_type(8))) short bf16x8;
typedef __attribute__((ext_vector_type(4))) float f32x4;

__device__ __forceinline__ unsigned short f2bf(float f) {
    unsigned u = __float_as_uint(f);
    u += 0x7fffu + ((u >> 16) & 1u);   // RNE
    return (unsigned short)(u >> 16);
}
__device__ __forceinline__ float bf2f(unsigned short h) {
    return __uint_as_float(((unsigned)h) << 16);
}

// async global->LDS, 16B per lane. LDS dest = wave-uniform base + lane*16.
// NOTE: LDS pointer must be converted via ADDRSPACECAST (pointer-type cast),
// NOT integer truncation — (unsigned)(uintptr_t) of a generic LDS pointer is
// garbage (round-1 corruption root cause).
__device__ __forceinline__ void gl_lds16(const void* g, void* l) {
    __builtin_amdgcn_global_load_lds(
        (const __attribute__((address_space(1))) void*)g,
        (__attribute__((address_space(3))) void*)l,
        16, 0, 0);
}

// chunk id -> (expert, base, len) from the 9-entry prefix array. Uniform scalar loop.
__device__ __forceinline__ bool chunk_lookup(const int* __restrict__ offs, int c, int csize,
                                             int& e, int& base, int& len) {
    int acc = 0;
#pragma unroll
    for (int i = 0; i < NE; i++) {
        int s = offs[i], t = offs[i + 1];
        int cc = (t - s + csize - 1) / csize;
        if (c < acc + cc) {
            e = i;
            base = s + (c - acc) * csize;
            len = (t - base < csize) ? (t - base) : csize;
            return true;
        }
        acc += cc;
    }
    return false;
}

// ---------------- prep chain ----------------
__global__ __launch_bounds__(64) void k_zero(int* __restrict__ ws_i) {
    int t = threadIdx.x;
    if (t < NE) ws_i[(WS_CNT >> 2) + t] = 0;
    if (t < NE) ws_i[(WS_CUR >> 2) + t] = 0;
}

__global__ __launch_bounds__(256) void k_hist(const int* __restrict__ sem, int* __restrict__ ws_i) {
    __shared__ int cnt[NE];
    int tid = threadIdx.x, lane = tid & 63;
    if (tid < NE) cnt[tid] = 0;
    __syncthreads();
    int s = sem[blockIdx.x * 256 + tid];
#pragma unroll
    for (int e = 0; e < NE; e++) {
        unsigned long long m = __ballot(s == e);
        if (lane == e) atomicAdd(&cnt[e], (int)__popcll(m));
    }
    __syncthreads();
    if (tid < NE) atomicAdd(ws_i + (WS_CNT >> 2) + tid, cnt[tid]);
}

__global__ __launch_bounds__(64) void k_scan(int* __restrict__ ws_i) {
    if (threadIdx.x == 0) {
        int acc = 0;
        int* offs = ws_i + (WS_OFFS >> 2);
        for (int e = 0; e < NE; e++) {
            offs[e] = acc;
            ws_i[(WS_CUR >> 2) + e] = acc;
            acc += ws_i[(WS_CNT >> 2) + e];
        }
        offs[NE] = acc;
    }
}

__global__ __launch_bounds__(256) void k_scatter(const int* __restrict__ sem, int* __restrict__ ws_i) {
    int tid = threadIdx.x, lane = tid & 63;
    int i = blockIdx.x * 256 + tid;
    int s = sem[i];
    int* perm = ws_i + (WS_PERM >> 2);
#pragma unroll
    for (int e = 0; e < NE; e++) {
        unsigned long long m = __ballot(s == e);
        if (s == e) {
            int leader = (int)__builtin_ctzll(m);
            int rank = (int)__popcll(m & ((1ull << lane) - 1ull));
            int bpos = 0;
            if (lane == leader) bpos = atomicAdd(ws_i + (WS_CUR >> 2) + e, (int)__popcll(m));
            bpos = __shfl(bpos, leader, 64);
            perm[bpos + rank] = i;
        }
    }
}

// ---------------- kernel 2: gather + fp32->bf16 convert of nodes ----------------
__global__ __launch_bounds__(256) void k_xgather(const float* __restrict__ x,
                                                 const int* __restrict__ perm,
                                                 unsigned short* __restrict__ xs) {
    int gid = blockIdx.x * 256 + threadIdx.x;    // 0 .. 2097151
    int st = gid >> 7;                           // sorted token
    int k8 = gid & 127;
    int src = perm[st];
    const float4* p = (const float4*)(x + (size_t)src * 1024 + k8 * 8);
    float4 a = p[0], b = p[1];
    unsigned r0 = (unsigned)f2bf(a.x) | ((unsigned)f2bf(a.y) << 16);
    unsigned r1 = (unsigned)f2bf(a.z) | ((unsigned)f2bf(a.w) << 16);
    unsigned r2 = (unsigned)f2bf(b.x) | ((unsigned)f2bf(b.y) << 16);
    unsigned r3 = (unsigned)f2bf(b.z) | ((unsigned)f2bf(b.w) << 16);
    *(uint4*)(xs + (size_t)st * 1024 + k8 * 8) = make_uint4(r0, r1, r2, r3);
}

// ---------------- kernel 3: W1|R1 -> bf16, transposed to [e][n=512][k=1024] ----------------
__global__ __launch_bounds__(256) void k_wcvt(const float* __restrict__ W1,
                                              const float* __restrict__ R1,
                                              unsigned short* __restrict__ wt) {
    __shared__ float tile[64][65];
    int k0 = blockIdx.x * 64;       // 0..960
    int n0 = blockIdx.y * 64;       // 0..448
    int e  = blockIdx.z;
    const float* src = (n0 < 256) ? (W1 + (size_t)e * 1024 * 256 + n0)
                                  : (R1 + (size_t)e * 1024 * 256 + (n0 - 256));
    int tid = threadIdx.x;
    int rr = tid >> 4;              // 0..15
    int cg = (tid & 15) * 4;
#pragma unroll
    for (int p = 0; p < 4; p++) {
        int kk = p * 16 + rr;
        float4 v = *(const float4*)(src + (size_t)(k0 + kk) * 256 + cg);
        tile[kk][cg] = v.x; tile[kk][cg + 1] = v.y; tile[kk][cg + 2] = v.z; tile[kk][cg + 3] = v.w;
    }
    __syncthreads();
    int nn = tid >> 3;              // 0..31
    int k8 = tid & 7;
#pragma unroll
    for (int p = 0; p < 2; p++) {
        int n = p * 32 + nn;
        unsigned w[4];
#pragma unroll
        for (int j = 0; j < 4; j++) {
            float f0 = tile[k8 * 8 + 2 * j][n];
            float f1 = tile[k8 * 8 + 2 * j + 1][n];
            w[j] = (unsigned)f2bf(f0) | ((unsigned)f2bf(f1) << 16);
        }
        *(uint4*)(wt + (size_t)(e * 512 + n0 + n) * 1024 + k0 + k8 * 8) =
            make_uint4(w[0], w[1], w[2], w[3]);
    }
}

// ---------------- kernel 3b: tail weights -> bf16 B^T tables ----------------
__global__ __launch_bounds__(256) void k_wcvt2(const float* __restrict__ W2,
                                               const float* __restrict__ W3,
                                               const float* __restrict__ W4,
                                               const float* __restrict__ R2,
                                               unsigned short* __restrict__ w2t,
                                               unsigned short* __restrict__ w3t,
                                               unsigned short* __restrict__ w4t,
                                               unsigned short* __restrict__ r2t) {
    int e = blockIdx.x, t = threadIdx.x;
    for (int idx = t; idx < 64 * 256; idx += 256) {
        int k = idx & 255, n = idx >> 8;
        w2t[(size_t)(e * 64 + n) * 256 + k] = f2bf(W2[(size_t)e * 16384 + k * 64 + n]);
    }
    for (int idx = t; idx < 32 * 64; idx += 256) {
        int k = idx & 63, n = idx >> 6;
        w3t[(size_t)(e * 32 + n) * 64 + k] = f2bf(W3[(size_t)e * 2048 + k * 32 + n]);
    }
    for (int idx = t; idx < 16 * 32; idx += 256) {
        int k = idx & 31, n = idx >> 5;
        w4t[(size_t)(e * 16 + n) * 32 + k] = (n < 14) ? f2bf(W4[(size_t)e * 448 + k * 14 + n])
                                                      : (unsigned short)0;
    }
    for (int idx = t; idx < 16 * 256; idx += 256) {
        int k = idx & 255, n = idx >> 8;
        r2t[(size_t)(e * 16 + n) * 256 + k] = (n < 3) ? f2bf(R2[(size_t)e * 768 + k * 3 + n])
                                                      : (unsigned short)0;
    }
}

// ---------------- kernel 4: layer-1 fused GEMM  h1 = relu(x @ [W1|R1] + [b1|rb1]) ----------------
// Round 7: retiled 128x128 -> 128x64 (grid 136x8 = 1088 blocks ~= 4.25/CU) to escape
// the 2-blocks/CU barrier-drain regime (m97 shape curve: 1/CU=320 TF, 4/CU=833 TF).
// 4 waves, each computes 32x64; global_load_lds width-16 staging (3 chunks/thread/k-iter).
__global__ __launch_bounds__(256) void k_gemm(const unsigned short* __restrict__ xs,
                                              const unsigned short* __restrict__ wt,
                                              const float* __restrict__ b1,
                                              const float* __restrict__ rb1,
                                              const int* __restrict__ ws_i,
                                              unsigned short* __restrict__ h1) {
    __shared__ __align__(16) short As[128 * 32];   // 8 KB
    __shared__ __align__(16) short Bs[64 * 32];    // 4 KB
    int e, base, len;
    if (!chunk_lookup(ws_i + (WS_OFFS >> 2), blockIdx.x, 128, e, base, len)) return;
    int n0 = blockIdx.y * 64;
    int tid = threadIdx.x;
    int wave = tid >> 6, lane = tid & 63;
    int quad = lane >> 4, lr = lane & 15;
    int wm = wave * 32;                            // wave's 32 M-rows

    f32x4 acc[2][4];
#pragma unroll
    for (int i = 0; i < 2; i++)
#pragma unroll
        for (int j = 0; j < 4; j++) acc[i][j] = (f32x4){0.f, 0.f, 0.f, 0.f};

    const unsigned short* Ag = xs + (size_t)base * 1024;
    const unsigned short* Bg = wt + (size_t)(e * 512 + n0) * 1024;

    for (int kb = 0; kb < 32; kb++) {
        __syncthreads();   // LDS safe to overwrite
        // A tile 128x32: 512 x 16B chunks (2/thread)
#pragma unroll
        for (int i = 0; i < 2; i++) {
            int g = i * 256 + wave * 64 + lane;
            int r = g >> 2, k8 = g & 3;
            gl_lds16(Ag + (size_t)r * 1024 + kb * 32 + k8 * 8,
                     As + (size_t)(i * 256 + wave * 64) * 8);
        }
        // B tile 64x32: 256 x 16B chunks (1/thread)
        {
            int g = wave * 64 + lane;
            int r = g >> 2, k8 = g & 3;
            gl_lds16(Bg + (size_t)r * 1024 + kb * 32 + k8 * 8,
                     Bs + (size_t)(wave * 64) * 8);
        }
        __syncthreads();   // compiler drains vmcnt before barrier -> DMA complete

        bf16x8 af[2], bfr[4];
#pragma unroll
        for (int im = 0; im < 2; im++)
            af[im] = *(const bf16x8*)(As + ((wm + im * 16 + lr) * 32 + quad * 8));
#pragma unroll
        for (int in = 0; in < 4; in++)
            bfr[in] = *(const bf16x8*)(Bs + ((in * 16 + lr) * 32 + quad * 8));
#pragma unroll
        for (int im = 0; im < 2; im++)
#pragma unroll
            for (int in = 0; in < 4; in++)
                acc[im][in] = __builtin_amdgcn_mfma_f32_16x16x32_bf16(af[im], bfr[in], acc[im][in], 0, 0, 0);
    }

    // epilogue: + bias, relu, store bf16. C/D layout: col=lane&15, row=quad*4+reg.
#pragma unroll
    for (int in = 0; in < 4; in++) {
        int gcol = n0 + in * 16 + lr;
        float bias = (gcol < 256) ? b1[e * 256 + gcol] : rb1[e * 256 + gcol - 256];
#pragma unroll
        for (int im = 0; im < 2; im++) {
#pragma unroll
            for (int v = 0; v < 4; v++) {
                int r = wm + im * 16 + quad * 4 + v;
                if (r < len) {
                    float val = fmaxf(acc[im][in][v] + bias, 0.f);
                    h1[(size_t)(base + r) * 512 + gcol] = f2bf(val);
                }
            }
        }
    }
}

// ---------------- kernel 5: MFMA tail — layers 2-4 + rot + masked scatter ----------------
// 4 waves/block; wave w owns tokens [16w,16w+16) of its 64-token chunk. No barriers:
// each wave writes and reads only its own h2s/h3s rows. Biases folded into MFMA C-init.
__global__ __launch_bounds__(256) void k_tail(const unsigned short* __restrict__ h1,
                                              const int* __restrict__ ws_i,
                                              const unsigned short* __restrict__ w2t,
                                              const unsigned short* __restrict__ w3t,
                                              const unsigned short* __restrict__ w4t,
                                              const unsigned short* __restrict__ r2t,
                                              const float* __restrict__ b2,
                                              const float* __restrict__ b3,
                                              const float* __restrict__ b4,
                                              const float* __restrict__ rb2,
                                              const int* __restrict__ lengths,
                                              float* __restrict__ out) {
    __shared__ __align__(16) unsigned short h2s[4][16][64];
    __shared__ __align__(16) unsigned short h3s[4][16][32];

    int e, base, len;
    if (!chunk_lookup(ws_i + (WS_OFFS >> 2), blockIdx.x, 64, e, base, len)) return;
    int tid = threadIdx.x, wave = tid >> 6, lane = tid & 63;
    int quad = lane >> 4, lr = lane & 15;
    int m0 = wave * 16;

    const unsigned short* Ap = h1 + (size_t)(base + m0) * 512;

    // layer2 (M=16,N=64,K=256) + rot (M=16,N=3pad16,K=256), A from global h1
    f32x4 acc2[4];
#pragma unroll
    for (int t = 0; t < 4; t++) {
        float bb = b2[e * 64 + t * 16 + lr];
        acc2[t] = (f32x4){bb, bb, bb, bb};
    }
    f32x4 accr;
    { float bb = (lr < 3) ? rb2[e * 3 + lr] : 0.f; accr = (f32x4){bb, bb, bb, bb}; }

    const unsigned short* W2e = w2t + (size_t)e * 64 * 256;
    const unsigned short* R2e = r2t + (size_t)e * 16 * 256;
#pragma unroll
    for (int kk = 0; kk < 8; kk++) {
        int k0 = kk * 32;
        bf16x8 a = *(const bf16x8*)(Ap + lr * 512 + k0 + quad * 8);
#pragma unroll
        for (int t = 0; t < 4; t++) {
            bf16x8 b = *(const bf16x8*)(W2e + (t * 16 + lr) * 256 + k0 + quad * 8);
            acc2[t] = __builtin_amdgcn_mfma_f32_16x16x32_bf16(a, b, acc2[t], 0, 0, 0);
        }
        bf16x8 ar = *(const bf16x8*)(Ap + lr * 512 + 256 + k0 + quad * 8);
        bf16x8 br = *(const bf16x8*)(R2e + lr * 256 + k0 + quad * 8);
        accr = __builtin_amdgcn_mfma_f32_16x16x32_bf16(ar, br, accr, 0, 0, 0);
    }
    // h2 = relu -> LDS bf16 (C layout: row=quad*4+v, col=lr per tile)
#pragma unroll
    for (int t = 0; t < 4; t++)
#pragma unroll
        for (int v = 0; v < 4; v++)
            h2s[wave][quad * 4 + v][t * 16 + lr] = f2bf(fmaxf(acc2[t][v], 0.f));

    // layer3 (M=16,N=32,K=64)
    f32x4 acc3[2];
#pragma unroll
    for (int t = 0; t < 2; t++) {
        float bb = b3[e * 32 + t * 16 + lr];
        acc3[t] = (f32x4){bb, bb, bb, bb};
    }
    const unsigned short* W3e = w3t + (size_t)e * 32 * 64;
#pragma unroll
    for (int kk = 0; kk < 2; kk++) {
        int k0 = kk * 32;
        bf16x8 a = *(const bf16x8*)(&h2s[wave][lr][k0 + quad * 8]);
#pragma unroll
        for (int t = 0; t < 2; t++) {
            bf16x8 b = *(const bf16x8*)(W3e + (t * 16 + lr) * 64 + k0 + quad * 8);
            acc3[t] = __builtin_amdgcn_mfma_f32_16x16x32_bf16(a, b, acc3[t], 0, 0, 0);
        }
    }
#pragma unroll
    for (int t = 0; t < 2; t++)
#pragma unroll
        for (int v = 0; v < 4; v++)
            h3s[wave][quad * 4 + v][t * 16 + lr] = f2bf(fmaxf(acc3[t][v], 0.f));

    // layer4 (M=16,N=14pad16,K=32): one MFMA
    f32x4 acc4;
    { float bb = (lr < 14) ? b4[e * 14 + lr] : 0.f; acc4 = (f32x4){bb, bb, bb, bb}; }
    {
        bf16x8 a = *(const bf16x8*)(&h3s[wave][lr][quad * 8]);
        bf16x8 b = *(const bf16x8*)(w4t + ((size_t)e * 16 + lr) * 32 + quad * 8);
        acc4 = __builtin_amdgcn_mfma_f32_16x16x32_bf16(a, b, acc4, 0, 0, 0);
    }

    // stores (masked): token row = quad*4+v
    const int* perm = ws_i + (WS_PERM >> 2);
#pragma unroll
    for (int v = 0; v < 4; v++) {
        int t = m0 + quad * 4 + v;
        if (t < len) {
            int token = perm[base + t];
            int bi = token >> 9, ni = token & 511;
            int valid = ni < lengths[bi];
            if (lr < 14) out[(size_t)token * 17 + lr] = valid ? acc4[v] : EPSV;
            if (lr < 3)  out[(size_t)token * 17 + 14 + lr] = valid ? accr[v] : EPSV;
        }
    }
}

extern "C" void kernel_launch(void* const* d_in, const int* in_sizes, int n_in,
                              void* d_out, int out_size, void* d_ws, size_t ws_size,
                              hipStream_t stream) {
    (void)in_sizes; (void)n_in; (void)out_size; (void)ws_size;
    const float* nodes   = (const float*)d_in[0];
    const int*   sem     = (const int*)d_in[1];
    const int*   lengths = (const int*)d_in[2];
    const float* W1 = (const float*)d_in[3];
    const float* b1 = (const float*)d_in[4];
    const float* W2 = (const float*)d_in[5];
    const float* b2 = (const float*)d_in[6];
    const float* W3 = (const float*)d_in[7];
    const float* b3 = (const float*)d_in[8];
    const float* W4 = (const float*)d_in[9];
    const float* b4 = (const float*)d_in[10];
    const float* R1  = (const float*)d_in[11];
    const float* rb1 = (const float*)d_in[12];
    const float* R2  = (const float*)d_in[13];
    const float* rb2 = (const float*)d_in[14];
    float* out = (float*)d_out;

    char* ws = (char*)d_ws;
    int* ws_i = (int*)ws;
    unsigned short* xs  = (unsigned short*)(ws + WS_XS);
    unsigned short* wt  = (unsigned short*)(ws + WS_WT);
    unsigned short* h1  = (unsigned short*)(ws + WS_H1);
    unsigned short* w2t = (unsigned short*)(ws + WS_W2T);
    unsigned short* w3t = (unsigned short*)(ws + WS_W3T);
    unsigned short* w4t = (unsigned short*)(ws + WS_W4T);
    unsigned short* r2t = (unsigned short*)(ws + WS_R2T);

    hipLaunchKernelGGL(k_zero, dim3(1), dim3(64), 0, stream, ws_i);
    hipLaunchKernelGGL(k_hist, dim3(64), dim3(256), 0, stream, sem, ws_i);
    hipLaunchKernelGGL(k_scan, dim3(1), dim3(64), 0, stream, ws_i);
    hipLaunchKernelGGL(k_scatter, dim3(64), dim3(256), 0, stream, sem, ws_i);
    hipLaunchKernelGGL(k_xgather, dim3(8192), dim3(256), 0, stream, nodes, (const int*)ws_i, xs);
    hipLaunchKernelGGL(k_wcvt, dim3(16, 8, 8), dim3(256), 0, stream, W1, R1, wt);
    hipLaunchKernelGGL(k_wcvt2, dim3(8), dim3(256), 0, stream, W2, W3, W4, R2, w2t, w3t, w4t, r2t);
    hipLaunchKernelGGL(k_gemm, dim3(MAXC128, 8), dim3(256), 0, stream,
                       (const unsigned short*)xs, (const unsigned short*)wt, b1, rb1,
                       (const int*)ws_i, h1);
    hipLaunchKernelGGL(k_tail, dim3(MAXC64), dim3(256), 0, stream,
                       (const unsigned short*)h1, (const int*)ws_i,
                       (const unsigned short*)w2t, (const unsigned short*)w3t,
                       (const unsigned short*)w4t, (const unsigned short*)r2t,
                       b2, b3, b4, rb2, lengths, out);
}

// Round 8
// 204.155 us; speedup vs baseline: 1.1855x; 1.1855x over previous
//
#include <hip/hip_runtime.h>
#include <stdint.h>

// Problem constants
#define T_TOK 16384     // 32*512 tokens
#define NE 8            // experts
#define EPSV 1e-8f
#define MAXC128 136     // max 128-token chunks: 128 + 7 partials, rounded up
#define MAXC64  264     // max 64-token chunks: 256 + 7 partials, rounded up

// ws layout (byte offsets). Total ~56.8 MiB.
#define WS_PERM   0                         // int[16384]
#define WS_PART   65536                     // int[64][8] per-block expert counts
#define WS_OFFS   67584                     // int[9]
#define WS_XS     131072                    // bf16[16512][1024] (slack rows for OOB-safe tile loads)
#define WS_WT     (WS_XS + 16512*1024*2)    // bf16[8][512][1024]  (W1|R1 transposed, B^T layout)
#define WS_H1     (WS_WT + 8*512*1024*2)    // bf16[16448][512] (64 slack rows)
#define WS_W2T    (WS_H1 + 16448*512*2)     // bf16[8][64][256]
#define WS_W3T    (WS_W2T + 8*64*256*2)     // bf16[8][32][64]
#define WS_W4T    (WS_W3T + 8*32*64*2)      // bf16[8][16][32]  (n>=14 zero)
#define WS_R2T    (WS_W4T + 8*16*32*2)      // bf16[8][16][256] (n>=3 zero)

typedef __attribute__((ext_vector_type(8))) short bf16x8;
typedef __attribute__((ext_vector_type(4))) float f32x4;

__device__ __forceinline__ unsigned short f2bf(float f) {
    unsigned u = __float_as_uint(f);
    u += 0x7fffu + ((u >> 16) & 1u);   // RNE
    return (unsigned short)(u >> 16);
}
__device__ __forceinline__ float bf2f(unsigned short h) {
    return __uint_as_float(((unsigned)h) << 16);
}

// async global->LDS, 16B per lane. LDS dest = wave-uniform base + lane*16.
// LDS pointer converted via ADDRSPACECAST (pointer-type cast), never integer
// truncation (round-1 corruption root cause).
__device__ __forceinline__ void gl_lds16(const void* g, void* l) {
    __builtin_amdgcn_global_load_lds(
        (const __attribute__((address_space(1))) void*)g,
        (__attribute__((address_space(3))) void*)l,
        16, 0, 0);
}

// chunk id -> (expert, base, len) from the 9-entry prefix array. Uniform scalar loop.
__device__ __forceinline__ bool chunk_lookup(const int* __restrict__ offs, int c, int csize,
                                             int& e, int& base, int& len) {
    int acc = 0;
#pragma unroll
    for (int i = 0; i < NE; i++) {
        int s = offs[i], t = offs[i + 1];
        int cc = (t - s + csize - 1) / csize;
        if (c < acc + cc) {
            e = i;
            base = s + (c - acc) * csize;
            len = (t - base < csize) ? (t - base) : csize;
            return true;
        }
        acc += cc;
    }
    return false;
}

// ---------------- prep: 2 kernels (hist -> scatter), no global atomics, no zero/scan ----
__global__ __launch_bounds__(256) void k_hist(const int* __restrict__ sem, int* __restrict__ ws_i) {
    __shared__ int cnt[NE];
    int tid = threadIdx.x, lane = tid & 63;
    if (tid < NE) cnt[tid] = 0;
    __syncthreads();
    int s = sem[blockIdx.x * 256 + tid];
#pragma unroll
    for (int e = 0; e < NE; e++) {
        unsigned long long m = __ballot(s == e);
        if (lane == e) atomicAdd(&cnt[e], (int)__popcll(m));
    }
    __syncthreads();
    if (tid < NE) ws_i[(WS_PART >> 2) + blockIdx.x * NE + tid] = cnt[tid];
}

// Each block deterministically recomputes its cursors from the partial-count table.
__global__ __launch_bounds__(256) void k_scatter(const int* __restrict__ sem, int* __restrict__ ws_i) {
    __shared__ int parts[64 * NE];
    __shared__ int tot[NE], preb[NE], ebase[NE + 1];
    __shared__ int cur[NE];
    int b = blockIdx.x, tid = threadIdx.x, lane = tid & 63;
    parts[tid] = ws_i[(WS_PART >> 2) + tid];
    parts[256 + tid] = ws_i[(WS_PART >> 2) + 256 + tid];
    __syncthreads();
    if (tid < NE) {
        int t = 0, p = 0;
        for (int bb = 0; bb < 64; bb++) {
            int v = parts[bb * NE + tid];
            t += v;
            if (bb < b) p += v;
        }
        tot[tid] = t; preb[tid] = p;
    }
    __syncthreads();
    if (tid == 0) {
        int base = 0;
        for (int e = 0; e < NE; e++) { ebase[e] = base; base += tot[e]; }
        ebase[NE] = base;
        if (b == 0)
            for (int e = 0; e <= NE; e++) ws_i[(WS_OFFS >> 2) + e] = ebase[e];
    }
    __syncthreads();
    if (tid < NE) cur[tid] = ebase[tid] + preb[tid];
    __syncthreads();
    int i = b * 256 + tid;
    int s = sem[i];
    int* perm = ws_i + (WS_PERM >> 2);
#pragma unroll
    for (int e = 0; e < NE; e++) {
        unsigned long long m = __ballot(s == e);
        if (s == e) {
            int leader = (int)__builtin_ctzll(m);
            int rank = (int)__popcll(m & ((1ull << lane) - 1ull));
            int bpos = 0;
            if (lane == leader) bpos = atomicAdd(&cur[e], (int)__popcll(m));
            bpos = __shfl(bpos, leader, 64);
            perm[bpos + rank] = i;
        }
    }
}

// ---------------- kernel 2: gather + fp32->bf16 convert of nodes ----------------
__global__ __launch_bounds__(256) void k_xgather(const float* __restrict__ x,
                                                 const int* __restrict__ perm,
                                                 unsigned short* __restrict__ xs) {
    int gid = blockIdx.x * 256 + threadIdx.x;    // 0 .. 2097151
    int st = gid >> 7;                           // sorted token
    int k8 = gid & 127;
    int src = perm[st];
    const float4* p = (const float4*)(x + (size_t)src * 1024 + k8 * 8);
    float4 a = p[0], b = p[1];
    unsigned r0 = (unsigned)f2bf(a.x) | ((unsigned)f2bf(a.y) << 16);
    unsigned r1 = (unsigned)f2bf(a.z) | ((unsigned)f2bf(a.w) << 16);
    unsigned r2 = (unsigned)f2bf(b.x) | ((unsigned)f2bf(b.y) << 16);
    unsigned r3 = (unsigned)f2bf(b.z) | ((unsigned)f2bf(b.w) << 16);
    *(uint4*)(xs + (size_t)st * 1024 + k8 * 8) = make_uint4(r0, r1, r2, r3);
}

// ---------------- kernel 3: W1|R1 -> bf16 [e][n=512][k=1024]; merged tail-weight convert ----
__global__ __launch_bounds__(256) void k_wcvt(const float* __restrict__ W1,
                                              const float* __restrict__ R1,
                                              const float* __restrict__ W2,
                                              const float* __restrict__ W3,
                                              const float* __restrict__ W4,
                                              const float* __restrict__ R2,
                                              unsigned short* __restrict__ wt,
                                              unsigned short* __restrict__ w2t,
                                              unsigned short* __restrict__ w3t,
                                              unsigned short* __restrict__ w4t,
                                              unsigned short* __restrict__ r2t) {
    __shared__ float tile[64][65];
    int k0 = blockIdx.x * 64;       // 0..960
    int n0 = blockIdx.y * 64;       // 0..448
    int e  = blockIdx.z;
    const float* src = (n0 < 256) ? (W1 + (size_t)e * 1024 * 256 + n0)
                                  : (R1 + (size_t)e * 1024 * 256 + (n0 - 256));
    int tid = threadIdx.x;
    int rr = tid >> 4;              // 0..15
    int cg = (tid & 15) * 4;
#pragma unroll
    for (int p = 0; p < 4; p++) {
        int kk = p * 16 + rr;
        float4 v = *(const float4*)(src + (size_t)(k0 + kk) * 256 + cg);
        tile[kk][cg] = v.x; tile[kk][cg + 1] = v.y; tile[kk][cg + 2] = v.z; tile[kk][cg + 3] = v.w;
    }
    __syncthreads();
    int nn = tid >> 3;              // 0..31
    int k8 = tid & 7;
#pragma unroll
    for (int p = 0; p < 2; p++) {
        int n = p * 32 + nn;
        unsigned w[4];
#pragma unroll
        for (int j = 0; j < 4; j++) {
            float f0 = tile[k8 * 8 + 2 * j][n];
            float f1 = tile[k8 * 8 + 2 * j + 1][n];
            w[j] = (unsigned)f2bf(f0) | ((unsigned)f2bf(f1) << 16);
        }
        *(uint4*)(wt + (size_t)(e * 512 + n0 + n) * 1024 + k0 + k8 * 8) =
            make_uint4(w[0], w[1], w[2], w[3]);
    }
    // merged tail-weight conversion: y==0 blocks, sliced over blockIdx.x (16 slices)
    if (blockIdx.y == 0) {
        int x = blockIdx.x;
        for (int j = tid; j < 1024; j += 256) {       // w2t: 16384/e -> 1024/slice
            int idx = x * 1024 + j; int k = idx & 255, n = idx >> 8;
            w2t[(size_t)(e * 64 + n) * 256 + k] = f2bf(W2[(size_t)e * 16384 + k * 64 + n]);
        }
        if (tid < 128) {                              // w3t: 2048/e -> 128/slice
            int idx = x * 128 + tid; int k = idx & 63, n = idx >> 6;
            w3t[(size_t)(e * 32 + n) * 64 + k] = f2bf(W3[(size_t)e * 2048 + k * 32 + n]);
        }
        if (tid < 32) {                               // w4t: 512/e -> 32/slice
            int idx = x * 32 + tid; int k = idx & 31, n = idx >> 5;
            w4t[(size_t)(e * 16 + n) * 32 + k] = (n < 14) ? f2bf(W4[(size_t)e * 448 + k * 14 + n])
                                                          : (unsigned short)0;
        }
        {                                             // r2t: 4096/e -> 256/slice
            int idx = x * 256 + tid; int k = idx & 255, n = idx >> 8;
            r2t[(size_t)(e * 16 + n) * 256 + k] = (n < 3) ? f2bf(R2[(size_t)e * 768 + k * 3 + n])
                                                          : (unsigned short)0;
        }
    }
}

// ---------------- kernel 4: layer-1 fused GEMM  h1 = relu(x @ [W1|R1] + [b1|rb1]) ----------------
// Round 8: 128x128 tile (revert R7), BK=64 (half the barrier pairs, 32 MFMA/wave/iter),
// XOR-swizzled LDS (slot (r,c) holds global chunk (r, c^(r&7)) -> fragment ds_read_b128
// spreads 16 lanes over 8 bank-groups = conflict-free). gl_lds width-16 staging.
__global__ __launch_bounds__(256) void k_gemm(const unsigned short* __restrict__ xs,
                                              const unsigned short* __restrict__ wt,
                                              const float* __restrict__ b1,
                                              const float* __restrict__ rb1,
                                              const int* __restrict__ ws_i,
                                              unsigned short* __restrict__ h1) {
    __shared__ __align__(16) short As[128 * 64];   // 16 KB
    __shared__ __align__(16) short Bs[128 * 64];   // 16 KB
    int e, base, len;
    if (!chunk_lookup(ws_i + (WS_OFFS >> 2), blockIdx.x, 128, e, base, len)) return;
    int n0 = blockIdx.y * 128;
    int tid = threadIdx.x;
    int wave = tid >> 6, lane = tid & 63;
    int quad = lane >> 4, lr = lane & 15;
    int wm = (wave & 1) * 64, wn = (wave >> 1) * 64;

    f32x4 acc[4][4];
#pragma unroll
    for (int i = 0; i < 4; i++)
#pragma unroll
        for (int j = 0; j < 4; j++) acc[i][j] = (f32x4){0.f, 0.f, 0.f, 0.f};

    const unsigned short* Ag = xs + (size_t)base * 1024;
    const unsigned short* Bg = wt + (size_t)(e * 512 + n0) * 1024;

    // per-thread staging sources (4 slots each for A and B), swizzled
    const unsigned short* srcA[4];
    const unsigned short* srcB[4];
    int dst[4];
#pragma unroll
    for (int i = 0; i < 4; i++) {
        int s = i * 256 + wave * 64 + lane;    // LDS slot (16B units)
        int r = s >> 3, c = s & 7;
        int cs = c ^ (r & 7);                  // swizzle: fetch chunk cs into slot c
        srcA[i] = Ag + (size_t)r * 1024 + cs * 8;
        srcB[i] = Bg + (size_t)r * 1024 + cs * 8;
        dst[i] = (i * 256 + wave * 64) * 8;    // wave-uniform base (+ lane*16 by HW)
    }

    for (int kb = 0; kb < 16; kb++) {
        __syncthreads();   // LDS safe to overwrite
#pragma unroll
        for (int i = 0; i < 4; i++) {
            gl_lds16(srcA[i] + kb * 64, As + dst[i]);
            gl_lds16(srcB[i] + kb * 64, Bs + dst[i]);
        }
        __syncthreads();   // vmcnt(0) drain: DMA complete

        bf16x8 af[2][4], bfr[2][4];
#pragma unroll
        for (int im = 0; im < 4; im++) {
            int r = wm + im * 16 + lr;
#pragma unroll
            for (int kh = 0; kh < 2; kh++) {
                int q = kh * 4 + quad;
                af[kh][im] = *(const bf16x8*)(As + (r * 8 + (q ^ (r & 7))) * 8);
            }
        }
#pragma unroll
        for (int in = 0; in < 4; in++) {
            int r = wn + in * 16 + lr;
#pragma unroll
            for (int kh = 0; kh < 2; kh++) {
                int q = kh * 4 + quad;
                bfr[kh][in] = *(const bf16x8*)(Bs + (r * 8 + (q ^ (r & 7))) * 8);
            }
        }
#pragma unroll
        for (int kh = 0; kh < 2; kh++)
#pragma unroll
            for (int im = 0; im < 4; im++)
#pragma unroll
                for (int in = 0; in < 4; in++)
                    acc[im][in] = __builtin_amdgcn_mfma_f32_16x16x32_bf16(af[kh][im], bfr[kh][in], acc[im][in], 0, 0, 0);
    }

    // epilogue: + bias, relu, store bf16. C/D layout: col=lane&15, row=quad*4+reg.
#pragma unroll
    for (int in = 0; in < 4; in++) {
        int gcol = n0 + wn + in * 16 + lr;
        float bias = (gcol < 256) ? b1[e * 256 + gcol] : rb1[e * 256 + gcol - 256];
#pragma unroll
        for (int im = 0; im < 4; im++) {
#pragma unroll
            for (int v = 0; v < 4; v++) {
                int r = wm + im * 16 + quad * 4 + v;
                if (r < len) {
                    float val = fmaxf(acc[im][in][v] + bias, 0.f);
                    h1[(size_t)(base + r) * 512 + gcol] = f2bf(val);
                }
            }
        }
    }
}

// ---------------- kernel 5: MFMA tail — layers 2-4 + rot + masked scatter ----------------
// 4 waves/block; wave w owns tokens [16w,16w+16) of its 64-token chunk. No barriers.
__global__ __launch_bounds__(256) void k_tail(const unsigned short* __restrict__ h1,
                                              const int* __restrict__ ws_i,
                                              const unsigned short* __restrict__ w2t,
                                              const unsigned short* __restrict__ w3t,
                                              const unsigned short* __restrict__ w4t,
                                              const unsigned short* __restrict__ r2t,
                                              const float* __restrict__ b2,
                                              const float* __restrict__ b3,
                                              const float* __restrict__ b4,
                                              const float* __restrict__ rb2,
                                              const int* __restrict__ lengths,
                                              float* __restrict__ out) {
    __shared__ __align__(16) unsigned short h2s[4][16][64];
    __shared__ __align__(16) unsigned short h3s[4][16][32];

    int e, base, len;
    if (!chunk_lookup(ws_i + (WS_OFFS >> 2), blockIdx.x, 64, e, base, len)) return;
    int tid = threadIdx.x, wave = tid >> 6, lane = tid & 63;
    int quad = lane >> 4, lr = lane & 15;
    int m0 = wave * 16;

    const unsigned short* Ap = h1 + (size_t)(base + m0) * 512;

    // layer2 (M=16,N=64,K=256) + rot (M=16,N=3pad16,K=256), A from global h1
    f32x4 acc2[4];
#pragma unroll
    for (int t = 0; t < 4; t++) {
        float bb = b2[e * 64 + t * 16 + lr];
        acc2[t] = (f32x4){bb, bb, bb, bb};
    }
    f32x4 accr;
    { float bb = (lr < 3) ? rb2[e * 3 + lr] : 0.f; accr = (f32x4){bb, bb, bb, bb}; }

    const unsigned short* W2e = w2t + (size_t)e * 64 * 256;
    const unsigned short* R2e = r2t + (size_t)e * 16 * 256;
#pragma unroll
    for (int kk = 0; kk < 8; kk++) {
        int k0 = kk * 32;
        bf16x8 a = *(const bf16x8*)(Ap + lr * 512 + k0 + quad * 8);
#pragma unroll
        for (int t = 0; t < 4; t++) {
            bf16x8 b = *(const bf16x8*)(W2e + (t * 16 + lr) * 256 + k0 + quad * 8);
            acc2[t] = __builtin_amdgcn_mfma_f32_16x16x32_bf16(a, b, acc2[t], 0, 0, 0);
        }
        bf16x8 ar = *(const bf16x8*)(Ap + lr * 512 + 256 + k0 + quad * 8);
        bf16x8 br = *(const bf16x8*)(R2e + lr * 256 + k0 + quad * 8);
        accr = __builtin_amdgcn_mfma_f32_16x16x32_bf16(ar, br, accr, 0, 0, 0);
    }
    // h2 = relu -> LDS bf16 (C layout: row=quad*4+v, col=lr per tile)
#pragma unroll
    for (int t = 0; t < 4; t++)
#pragma unroll
        for (int v = 0; v < 4; v++)
            h2s[wave][quad * 4 + v][t * 16 + lr] = f2bf(fmaxf(acc2[t][v], 0.f));

    // layer3 (M=16,N=32,K=64)
    f32x4 acc3[2];
#pragma unroll
    for (int t = 0; t < 2; t++) {
        float bb = b3[e * 32 + t * 16 + lr];
        acc3[t] = (f32x4){bb, bb, bb, bb};
    }
    const unsigned short* W3e = w3t + (size_t)e * 32 * 64;
#pragma unroll
    for (int kk = 0; kk < 2; kk++) {
        int k0 = kk * 32;
        bf16x8 a = *(const bf16x8*)(&h2s[wave][lr][k0 + quad * 8]);
#pragma unroll
        for (int t = 0; t < 2; t++) {
            bf16x8 b = *(const bf16x8*)(W3e + (t * 16 + lr) * 64 + k0 + quad * 8);
            acc3[t] = __builtin_amdgcn_mfma_f32_16x16x32_bf16(a, b, acc3[t], 0, 0, 0);
        }
    }
#pragma unroll
    for (int t = 0; t < 2; t++)
#pragma unroll
        for (int v = 0; v < 4; v++)
            h3s[wave][quad * 4 + v][t * 16 + lr] = f2bf(fmaxf(acc3[t][v], 0.f));

    // layer4 (M=16,N=14pad16,K=32): one MFMA
    f32x4 acc4;
    { float bb = (lr < 14) ? b4[e * 14 + lr] : 0.f; acc4 = (f32x4){bb, bb, bb, bb}; }
    {
        bf16x8 a = *(const bf16x8*)(&h3s[wave][lr][quad * 8]);
        bf16x8 b = *(const bf16x8*)(w4t + ((size_t)e * 16 + lr) * 32 + quad * 8);
        acc4 = __builtin_amdgcn_mfma_f32_16x16x32_bf16(a, b, acc4, 0, 0, 0);
    }

    // stores (masked): token row = quad*4+v
    const int* perm = ws_i + (WS_PERM >> 2);
#pragma unroll
    for (int v = 0; v < 4; v++) {
        int t = m0 + quad * 4 + v;
        if (t < len) {
            int token = perm[base + t];
            int bi = token >> 9, ni = token & 511;
            int valid = ni < lengths[bi];
            if (lr < 14) out[(size_t)token * 17 + lr] = valid ? acc4[v] : EPSV;
            if (lr < 3)  out[(size_t)token * 17 + 14 + lr] = valid ? accr[v] : EPSV;
        }
    }
}

extern "C" void kernel_launch(void* const* d_in, const int* in_sizes, int n_in,
                              void* d_out, int out_size, void* d_ws, size_t ws_size,
                              hipStream_t stream) {
    (void)in_sizes; (void)n_in; (void)out_size; (void)ws_size;
    const float* nodes   = (const float*)d_in[0];
    const int*   sem     = (const int*)d_in[1];
    const int*   lengths = (const int*)d_in[2];
    const float* W1 = (const float*)d_in[3];
    const float* b1 = (const float*)d_in[4];
    const float* W2 = (const float*)d_in[5];
    const float* b2 = (const float*)d_in[6];
    const float* W3 = (const float*)d_in[7];
    const float* b3 = (const float*)d_in[8];
    const float* W4 = (const float*)d_in[9];
    const float* b4 = (const float*)d_in[10];
    const float* R1  = (const float*)d_in[11];
    const float* rb1 = (const float*)d_in[12];
    const float* R2  = (const float*)d_in[13];
    const float* rb2 = (const float*)d_in[14];
    float* out = (float*)d_out;

    char* ws = (char*)d_ws;
    int* ws_i = (int*)ws;
    unsigned short* xs  = (unsigned short*)(ws + WS_XS);
    unsigned short* wt  = (unsigned short*)(ws + WS_WT);
    unsigned short* h1  = (unsigned short*)(ws + WS_H1);
    unsigned short* w2t = (unsigned short*)(ws + WS_W2T);
    unsigned short* w3t = (unsigned short*)(ws + WS_W3T);
    unsigned short* w4t = (unsigned short*)(ws + WS_W4T);
    unsigned short* r2t = (unsigned short*)(ws + WS_R2T);

    hipLaunchKernelGGL(k_hist, dim3(64), dim3(256), 0, stream, sem, ws_i);
    hipLaunchKernelGGL(k_scatter, dim3(64), dim3(256), 0, stream, sem, ws_i);
    hipLaunchKernelGGL(k_xgather, dim3(8192), dim3(256), 0, stream, nodes, (const int*)ws_i, xs);
    hipLaunchKernelGGL(k_wcvt, dim3(16, 8, 8), dim3(256), 0, stream,
                       W1, R1, W2, W3, W4, R2, wt, w2t, w3t, w4t, r2t);
    hipLaunchKernelGGL(k_gemm, dim3(MAXC128, 4), dim3(256), 0, stream,
                       (const unsigned short*)xs, (const unsigned short*)wt, b1, rb1,
                       (const int*)ws_i, h1);
    hipLaunchKernelGGL(k_tail, dim3(MAXC64), dim3(256), 0, stream,
                       (const unsigned short*)h1, (const int*)ws_i,
                       (const unsigned short*)w2t, (const unsigned short*)w3t,
                       (const unsigned short*)w4t, (const unsigned short*)r2t,
                       b2, b3, b4, rb2, lengths, out);
}